// Round 2
// baseline (1181.468 us; speedup 1.0000x reference)
//
#include <hip/hip_runtime.h>

// QuantizedLinear via int8 MFMA, 256x256-tile 8-phase pipelined GEMM.
// out[M,N] = x[M,K] @ W[N,K]^T + bias; W int4 exact in i8, x per-row i8.
// BK=128 = one scale group; i32 accumulate per group (exact), drained to f32
// with group scale each phase-quadrant. Counted vmcnt (never 0 in loop),
// 1 barrier/phase, setprio around MFMA cluster, c^(row&7) 16B-chunk swizzle.
//
// R1 -> R2: __launch_bounds__(512,2) made the compiler cap at 128 VGPR
// (16 waves/CU target) and spill accf[8][4][4] -> 2.7 GB/dispatch scratch
// traffic (WRITE_SIZE 1.57 GB vs 134 MB output). 512-thread block + 128 KiB
// LDS is 1 block/CU regardless; declare (512,1) so the cap is 256 VGPR and
// the 128-reg accumulator lives in registers.

typedef int i32x4 __attribute__((ext_vector_type(4)));

#define GAS __attribute__((address_space(1)))
#define LAS __attribute__((address_space(3)))

static constexpr int M_DIM = 8192;
static constexpr int N_DIM = 4096;
static constexpr int K_DIM = 4096;

// ---------------- x fp32 -> i8 per-row (one block per row of 4096) ----------------
__global__ __launch_bounds__(256) void quant_x(const float* __restrict__ x,
                                               signed char* __restrict__ xq,
                                               float* __restrict__ sx) {
    const int row = blockIdx.x;
    const int tid = threadIdx.x;
    const float* xr = x + (size_t)row * K_DIM;
    float4 v[4];
#pragma unroll
    for (int i = 0; i < 4; ++i) v[i] = *(const float4*)(xr + i * 1024 + tid * 4);
    float m = 0.f;
#pragma unroll
    for (int i = 0; i < 4; ++i)
        m = fmaxf(m, fmaxf(fmaxf(fabsf(v[i].x), fabsf(v[i].y)),
                           fmaxf(fabsf(v[i].z), fabsf(v[i].w))));
#pragma unroll
    for (int off = 32; off >= 1; off >>= 1) m = fmaxf(m, __shfl_xor(m, off, 64));
    __shared__ float wm[4];
    if ((tid & 63) == 0) wm[tid >> 6] = m;
    __syncthreads();
    m = fmaxf(fmaxf(wm[0], wm[1]), fmaxf(wm[2], wm[3]));
    const float inv = 127.f / m;
    if (tid == 0) sx[row] = m / 127.f;
#pragma unroll
    for (int i = 0; i < 4; ++i) {
        int b0 = (int)rintf(v[i].x * inv) & 255;
        int b1 = (int)rintf(v[i].y * inv) & 255;
        int b2 = (int)rintf(v[i].z * inv) & 255;
        int b3 = (int)rintf(v[i].w * inv) & 255;
        *(int*)(xq + (size_t)row * K_DIM + i * 1024 + tid * 4) =
            b0 | (b1 << 8) | (b2 << 16) | (b3 << 24);
    }
}

// ---------------- packed int4 -> raw i8 (values q-8 in [-8,7], NO scale) ----------------
__global__ __launch_bounds__(256) void unpack_w(const int* __restrict__ wp,
                                                signed char* __restrict__ wq) {
    const int t = blockIdx.x * 256 + threadIdx.x;   // 4 packed words -> 8 bytes out
    int4 p = *(const int4*)(wp + (size_t)t * 4);
    int pv[4] = {p.x, p.y, p.z, p.w};
    int w01 = (((pv[0] & 15) - 8) & 255) | (((((pv[0] >> 4) & 15) - 8) & 255) << 8) |
              ((((pv[1] & 15) - 8) & 255) << 16) | (((((pv[1] >> 4) & 15) - 8) & 255) << 24);
    int w23 = (((pv[2] & 15) - 8) & 255) | (((((pv[2] >> 4) & 15) - 8) & 255) << 8) |
              ((((pv[3] & 15) - 8) & 255) << 16) | (((((pv[3] >> 4) & 15) - 8) & 255) << 24);
    *(int2*)(wq + (size_t)t * 8) = make_int2(w01, w23);
}

// ---------------- scales [N][32] -> scalesT [32][N] (coalesced gemm reads) ----------------
__global__ __launch_bounds__(256) void transp_scales(const float* __restrict__ s,
                                                     float* __restrict__ st) {
    const int t = blockIdx.x * 256 + threadIdx.x;   // over 4096*32
    st[(size_t)(t & 31) * N_DIM + (t >> 5)] = s[t];
}

// ---------------- i8 GEMM, B^T, 256x256 tile, BK=128, 8-phase pipeline ----------------
// 512 thr = 8 waves (2M x 4N); per-wave output 128x64 = 8x4 frags of 16x16.
// LDS 128 KiB: A [2buf][2half(128 rows)][128 rows x 128 B], B same at +64 KiB.
// Row = 128 B = 8 chunks of 16 B; chunk c stored at slot c ^ (row&7).
// Iteration = 2 K-tiles (t0 in buf0 phases 1-4, t1 in buf1 phases 5-8).
// Each phase: stage 1 union-half (2 gload_lds/thread) -> other buffer,
// 12 ds_read_b128, 16 MFMA (setprio 1), drain quadrant, counted vmcnt, barrier.
//
// Union-halves (stage & consumption granularity):
//   A-uh h = rows {wr*128 + h*64 + [0,64)}  : read in phases with mh==h
//   B-uh h = rows {wc*64  + h*32 + [0,32)}  : read in phases with nh==h
// Phase quadrants: (mh,nh) = (0,0),(0,1),(1,0),(1,1).
// Stage order per 4-phase group: A-uh0, B-uh0, B-uh1, A-uh1 (next tile).
// Wait derivation (2 stage loads/phase; +4 scale loads in ph1 & ph5):
//   end-ph1: need B-uh1(cur) [staged prev ph7]; newer = ph8(2)+ph1(2+4) = 8 -> vmcnt(8)
//   end-ph2: need A-uh1(cur) [prev ph8];      newer = ph1(6)+ph2(2)     = 8 -> vmcnt(8)
//   end-ph3: nothing new -> memory clobber only
//   end-ph4: need A-uh0,B-uh0(t1) [ph1,ph2];  newer = ph3(2)+ph4(2)     = 4 -> vmcnt(4)
//   phases 5-8 symmetric. Max outstanding 12; never vmcnt(0) in loop.

#define STAGE_A(BUF, H, TAU) do { \
  _Pragma("unroll") \
  for (int r_ = 0; r_ < 2; ++r_) { \
    const int ra_ = (H) * 64 + wv * 8 + (l >> 3); \
    const int c_  = (l & 7) ^ (l >> 3); \
    const signed char* sA_ = Aq + (size_t)(m0 + r_ * 128 + ra_) * K_DIM \
                                + (size_t)(TAU) * 128 + c_ * 16; \
    __builtin_amdgcn_global_load_lds((const GAS void*)sA_, \
        (LAS void*)(lds + ((BUF) * 2 + r_) * 16384 + ((H) * 64 + wv * 8) * 128), 16, 0, 0); \
  } \
} while (0)

#define STAGE_B(BUF, H, TAU) do { \
  _Pragma("unroll") \
  for (int r_ = 0; r_ < 2; ++r_) { \
    const int rb_ = (wv >> 2) * 64 + (H) * 32 + (wv & 3) * 8 + (l >> 3); \
    const int c_  = (l & 7) ^ (l >> 3); \
    const signed char* sB_ = Bq + (size_t)(n0 + r_ * 128 + rb_) * K_DIM \
                                + (size_t)(TAU) * 128 + c_ * 16; \
    __builtin_amdgcn_global_load_lds((const GAS void*)sB_, \
        (LAS void*)(lds + 65536 + ((BUF) * 2 + r_) * 16384 \
                    + ((wv >> 2) * 64 + (H) * 32 + (wv & 3) * 8) * 128), 16, 0, 0); \
  } \
} while (0)

#define LOAD_SJ(DST, G) do { \
  _Pragma("unroll") \
  for (int j_ = 0; j_ < 4; ++j_) \
    DST[j_] = scalesT[(size_t)(G) * N_DIM + n0 + wc * 64 + j_ * 16 + lr]; \
} while (0)

#define PHASE(B, MH, NH, S0, S1) do { \
  i32x4 aF0_[4], aF1_[4], bF0_[2], bF1_[2]; \
  _Pragma("unroll") \
  for (int nj = 0; nj < 2; ++nj) { \
    const int rb = ((wc & 1) << 6) + (NH) * 32 + nj * 16 + lr; \
    const signed char* bp = lds + 65536 + ((B) * 2 + (wc >> 1)) * 16384 + rb * 128; \
    bF0_[nj] = *(const i32x4*)(bp + ((quad       ^ (rb & 7)) << 4)); \
    bF1_[nj] = *(const i32x4*)(bp + (((4 | quad) ^ (rb & 7)) << 4)); \
  } \
  _Pragma("unroll") \
  for (int mi = 0; mi < 4; ++mi) { \
    const int ra = (MH) * 64 + mi * 16 + lr; \
    const signed char* ap = lds + ((B) * 2 + wr) * 16384 + ra * 128; \
    aF0_[mi] = *(const i32x4*)(ap + ((quad       ^ (ra & 7)) << 4)); \
    aF1_[mi] = *(const i32x4*)(ap + (((4 | quad) ^ (ra & 7)) << 4)); \
  } \
  i32x4 ci_[4][2]; \
  __builtin_amdgcn_s_setprio(1); \
  _Pragma("unroll") \
  for (int mi = 0; mi < 4; ++mi) { \
    ci_[mi][0] = __builtin_amdgcn_mfma_i32_16x16x64_i8(aF0_[mi], bF0_[0], izero, 0, 0, 0); \
    ci_[mi][1] = __builtin_amdgcn_mfma_i32_16x16x64_i8(aF0_[mi], bF0_[1], izero, 0, 0, 0); \
  } \
  _Pragma("unroll") \
  for (int mi = 0; mi < 4; ++mi) { \
    ci_[mi][0] = __builtin_amdgcn_mfma_i32_16x16x64_i8(aF1_[mi], bF1_[0], ci_[mi][0], 0, 0, 0); \
    ci_[mi][1] = __builtin_amdgcn_mfma_i32_16x16x64_i8(aF1_[mi], bF1_[1], ci_[mi][1], 0, 0, 0); \
  } \
  __builtin_amdgcn_s_setprio(0); \
  _Pragma("unroll") \
  for (int mi = 0; mi < 4; ++mi) \
    _Pragma("unroll") \
    for (int r = 0; r < 4; ++r) { \
      accf[(MH) * 4 + mi][(NH) * 2 + 0][r] += (S0) * (float)ci_[mi][0][r]; \
      accf[(MH) * 4 + mi][(NH) * 2 + 1][r] += (S1) * (float)ci_[mi][1][r]; \
    } \
} while (0)

#define VMW(N) asm volatile("s_waitcnt vmcnt(" #N ")" ::: "memory")
#define CLB()  asm volatile("" ::: "memory")
#define BAR()  __builtin_amdgcn_s_barrier()

__global__ __launch_bounds__(512, 1) void gemm_i8(const signed char* __restrict__ Aq,
                                                  const signed char* __restrict__ Bq,
                                                  const float* __restrict__ scalesT,
                                                  const float* __restrict__ sx,
                                                  const float* __restrict__ bias,
                                                  float* __restrict__ C) {
    __shared__ signed char lds[131072];

    const int tid  = threadIdx.x;
    const int l    = tid & 63;
    const int wv   = tid >> 6;      // 0..7
    const int wr   = wv >> 2;       // 0..1  (M half of 256)
    const int wc   = wv & 3;        // 0..3  (N quarter of 256)
    const int lr   = l & 15;
    const int quad = l >> 4;

    // XCD-aware swizzle: 512 wgs, 64/XCD as an 8x8 tile block (bijective).
    const int bid = blockIdx.x;
    const int xcd = bid & 7, kk = bid >> 3;
    const int bx = (xcd & 1) * 8 + (kk & 7);     // n-tile 0..15
    const int by = (xcd >> 1) * 8 + (kk >> 3);   // m-tile 0..31
    const int m0 = by * 256, n0 = bx * 256;

    float accf[8][4][4];
#pragma unroll
    for (int i = 0; i < 8; ++i)
#pragma unroll
        for (int j = 0; j < 4; ++j)
#pragma unroll
            for (int r = 0; r < 4; ++r) accf[i][j][r] = 0.f;

    const i32x4 izero = {0, 0, 0, 0};
    float sjc0[4], sjc1[4], sjn0[4], sjn1[4];

    // Prologue: scales for tiles 0,1; stage tile 0 (order = steady-state ph5-8).
    LOAD_SJ(sjc0, 0);
    LOAD_SJ(sjc1, 1);
    STAGE_A(0, 0, 0);
    STAGE_B(0, 0, 0);
    STAGE_B(0, 1, 0);
    STAGE_A(0, 1, 0);
    VMW(4);
    BAR();

#pragma unroll 1
    for (int it = 0; it < 16; ++it) {
        const int t1  = it * 2 + 1;
        const int tn0 = (it * 2 + 2) & 31;
        const int tn1 = (it * 2 + 3) & 31;

        STAGE_A(1, 0, t1); LOAD_SJ(sjn0, tn0);
        PHASE(0, 0, 0, sjc0[0], sjc0[1]);
        VMW(8); BAR();

        STAGE_B(1, 0, t1);
        PHASE(0, 0, 1, sjc0[2], sjc0[3]);
        VMW(8); BAR();

        STAGE_B(1, 1, t1);
        PHASE(0, 1, 0, sjc0[0], sjc0[1]);
        CLB(); BAR();

        STAGE_A(1, 1, t1);
        PHASE(0, 1, 1, sjc0[2], sjc0[3]);
        VMW(4); BAR();

        STAGE_A(0, 0, tn0); LOAD_SJ(sjn1, tn1);
        PHASE(1, 0, 0, sjc1[0], sjc1[1]);
        VMW(8); BAR();

        STAGE_B(0, 0, tn0);
        PHASE(1, 0, 1, sjc1[2], sjc1[3]);
        VMW(8); BAR();

        STAGE_B(0, 1, tn0);
        PHASE(1, 1, 0, sjc1[0], sjc1[1]);
        CLB(); BAR();

        STAGE_A(0, 1, tn0);
        PHASE(1, 1, 1, sjc1[2], sjc1[3]);
        VMW(4); BAR();

#pragma unroll
        for (int j = 0; j < 4; ++j) { sjc0[j] = sjn0[j]; sjc1[j] = sjn1[j]; }
    }

    // Drain leftover wrap-staged DMA before LDS goes away with the block.
    asm volatile("s_waitcnt vmcnt(0)" ::: "memory");

    // Epilogue: C/D layout col=lane&15, row=quad*4+reg (verified, dtype-independent)
    float sxr[8][4];
#pragma unroll
    for (int i = 0; i < 8; ++i)
#pragma unroll
        for (int r = 0; r < 4; ++r)
            sxr[i][r] = sx[m0 + wr * 128 + i * 16 + quad * 4 + r];
#pragma unroll
    for (int j = 0; j < 4; ++j) {
        const int gn = n0 + wc * 64 + j * 16 + lr;
        const float bv = bias[gn];
#pragma unroll
        for (int i = 0; i < 8; ++i) {
            const size_t gm = (size_t)m0 + wr * 128 + i * 16 + quad * 4;
#pragma unroll
            for (int r = 0; r < 4; ++r)
                C[(gm + r) * N_DIM + gn] = accf[i][j][r] * sxr[i][r] + bv;
        }
    }
}

extern "C" void kernel_launch(void* const* d_in, const int* in_sizes, int n_in,
                              void* d_out, int out_size, void* d_ws, size_t ws_size,
                              hipStream_t stream) {
    const float* x      = (const float*)d_in[0];   // [4,2048,4096] fp32
    const int*   wp     = (const int*)d_in[1];     // [4096,2048] int32 (uint8 semantics)
    const float* scales = (const float*)d_in[2];   // [4096,32]
    const float* bias   = (const float*)d_in[4];   // [4096]
    float* out = (float*)d_out;

    signed char* Xq = (signed char*)d_ws;                                   // 32 MB
    signed char* Wq = (signed char*)d_ws + (size_t)M_DIM * K_DIM;           // +16 MB
    float* sx  = (float*)((char*)d_ws + (size_t)M_DIM * K_DIM + (size_t)N_DIM * K_DIM);          // +32 KB
    float* scT = (float*)((char*)d_ws + (size_t)M_DIM * K_DIM + (size_t)N_DIM * K_DIM + 32768);  // +512 KB

    quant_x<<<M_DIM, 256, 0, stream>>>(x, Xq, sx);
    unpack_w<<<(N_DIM * (K_DIM / 2) / 4) / 256, 256, 0, stream>>>(wp, Wq);
    transp_scales<<<(N_DIM * 32) / 256, 256, 0, stream>>>(scales, scT);
    gemm_i8<<<dim3(512), 512, 0, stream>>>(Xq, Wq, scT, sx, bias, out);
}

// Round 3
// 450.177 us; speedup vs baseline: 2.6244x; 2.6244x over previous
//
#include <hip/hip_runtime.h>

// QuantizedLinear via int8 MFMA, 256x128-tile 8-phase pipelined GEMM.
// out[M,N] = x[M,K] @ W[N,K]^T + bias; W int4 exact in i8, x per-row i8.
// BK=128 = one scale group; i32 accumulate per group (exact), drained to f32
// with group scale each phase-quadrant. Counted vmcnt (never 0 in loop),
// 1 barrier/phase, setprio around MFMA cluster, c^(row&7) 16B-chunk swizzle.
//
// R1/R2 lesson: 256x256 tile (accf=128 f32/lane) + drain transients needs
// ~250 VGPR; hipcc capped at 128 regardless of __launch_bounds__(512,{1,2})
// -> accf spilled, 2.7 GB/dispatch scratch traffic, 950 us. Fix: halve the
// per-lane accumulator (BM=256,BN=128, 8 waves 4Mx2N, per-wave 64x64,
// accf[4][4][4]=64) AND pin the allocator with amdgpu_waves_per_eu(2,2)
// (LDS 96 KiB = 1 block/CU anyway, so 2 waves/EU is the real occupancy).

typedef int i32x4 __attribute__((ext_vector_type(4)));

#define GAS __attribute__((address_space(1)))
#define LAS __attribute__((address_space(3)))

static constexpr int M_DIM = 8192;
static constexpr int N_DIM = 4096;
static constexpr int K_DIM = 4096;

// ---------------- x fp32 -> i8 per-row (one block per row of 4096) ----------------
__global__ __launch_bounds__(256) void quant_x(const float* __restrict__ x,
                                               signed char* __restrict__ xq,
                                               float* __restrict__ sx) {
    const int row = blockIdx.x;
    const int tid = threadIdx.x;
    const float* xr = x + (size_t)row * K_DIM;
    float4 v[4];
#pragma unroll
    for (int i = 0; i < 4; ++i) v[i] = *(const float4*)(xr + i * 1024 + tid * 4);
    float m = 0.f;
#pragma unroll
    for (int i = 0; i < 4; ++i)
        m = fmaxf(m, fmaxf(fmaxf(fabsf(v[i].x), fabsf(v[i].y)),
                           fmaxf(fabsf(v[i].z), fabsf(v[i].w))));
#pragma unroll
    for (int off = 32; off >= 1; off >>= 1) m = fmaxf(m, __shfl_xor(m, off, 64));
    __shared__ float wm[4];
    if ((tid & 63) == 0) wm[tid >> 6] = m;
    __syncthreads();
    m = fmaxf(fmaxf(wm[0], wm[1]), fmaxf(wm[2], wm[3]));
    const float inv = 127.f / m;
    if (tid == 0) sx[row] = m / 127.f;
#pragma unroll
    for (int i = 0; i < 4; ++i) {
        int b0 = (int)rintf(v[i].x * inv) & 255;
        int b1 = (int)rintf(v[i].y * inv) & 255;
        int b2 = (int)rintf(v[i].z * inv) & 255;
        int b3 = (int)rintf(v[i].w * inv) & 255;
        *(int*)(xq + (size_t)row * K_DIM + i * 1024 + tid * 4) =
            b0 | (b1 << 8) | (b2 << 16) | (b3 << 24);
    }
}

// ---------------- packed int4 -> raw i8 (values q-8 in [-8,7], NO scale) ----------------
__global__ __launch_bounds__(256) void unpack_w(const int* __restrict__ wp,
                                                signed char* __restrict__ wq) {
    const int t = blockIdx.x * 256 + threadIdx.x;   // 4 packed words -> 8 bytes out
    int4 p = *(const int4*)(wp + (size_t)t * 4);
    int pv[4] = {p.x, p.y, p.z, p.w};
    int w01 = (((pv[0] & 15) - 8) & 255) | (((((pv[0] >> 4) & 15) - 8) & 255) << 8) |
              ((((pv[1] & 15) - 8) & 255) << 16) | (((((pv[1] >> 4) & 15) - 8) & 255) << 24);
    int w23 = (((pv[2] & 15) - 8) & 255) | (((((pv[2] >> 4) & 15) - 8) & 255) << 8) |
              ((((pv[3] & 15) - 8) & 255) << 16) | (((((pv[3] >> 4) & 15) - 8) & 255) << 24);
    *(int2*)(wq + (size_t)t * 8) = make_int2(w01, w23);
}

// ---------------- scales [N][32] -> scalesT [32][N] (coalesced gemm reads) ----------------
__global__ __launch_bounds__(256) void transp_scales(const float* __restrict__ s,
                                                     float* __restrict__ st) {
    const int t = blockIdx.x * 256 + threadIdx.x;   // over 4096*32
    st[(size_t)(t & 31) * N_DIM + (t >> 5)] = s[t];
}

// ---------------- i8 GEMM, B^T, 256x128 tile, BK=128, 8-phase pipeline ----------------
// 512 thr = 8 waves (4M x 2N); per-wave output 64x64 = 4x4 frags of 16x16.
// LDS 96 KiB: A [2buf][256 x 128 B] (64 KiB), B [2buf][128 x 128 B] (32 KiB @ +64 KiB).
// Row = 128 B = 8 chunks of 16 B; chunk c stored at slot c ^ (row&7).
// Iteration = 2 K-tiles (ta=2it in buf0 ph1-4, tb=2it+1 in buf1 ph5-8).
//
// Union-halves (stage & consumption granularity):
//   A-uh h = 32-row stripes with parity h (rows r: (r>>5)&1 == h), 16 KB, 2 loads/thr
//   B-uh h = 32-row stripes parity h of 128,                        8 KB, 1 load/thr
// Phase quadrant (mh,nh): wave reads A rows wr*64+mh*32+[0,32) (stripe parity mh),
// B rows wc*64+nh*32+[0,32) (parity nh). 8 MFMA + 16-elem drain per phase.
// Stage order per tile: A-uh0, B-uh0, B-uh1, A-uh1 (+4 scale loads w/ A-uh0).
// Ledger (issues/phase = 6,1,1,2|6,1,1,2):
//   end-ph1 guard Buh1(ta)@pv-ph7: newer pv8(2)+p1(6) = 8 -> vmcnt(8)
//   end-ph2 guard Auh1(ta)@pv-ph8: newer p1(6)+p2(1)  = 7 -> vmcnt(7)
//   end-ph3 none -> clobber only
//   end-ph4 guard Auh0,Buh0(tb)@p1,p2: newer p3(1)+p4(2) = 3 -> vmcnt(3)
//   ph5-8 symmetric. Max ~10 outstanding; never vmcnt(0) in loop.

#define STAGE_AH(BUF, H, TAU) do { \
  _Pragma("unroll") \
  for (int r_ = 0; r_ < 2; ++r_) { \
    const int g_ = r_ * 8 + wv; \
    const int rbase_ = (g_ >> 2) * 64 + (H) * 32 + (g_ & 3) * 8; \
    const int c_ = (l & 7) ^ (l >> 3); \
    const signed char* sA_ = Aq + (size_t)(m0 + rbase_ + (l >> 3)) * K_DIM \
                                + (size_t)(TAU) * 128 + c_ * 16; \
    __builtin_amdgcn_global_load_lds((const GAS void*)sA_, \
        (LAS void*)(lds + (BUF) * 32768 + rbase_ * 128), 16, 0, 0); \
  } \
} while (0)

#define STAGE_BH(BUF, H, TAU) do { \
    const int rbase_ = (wv >> 2) * 64 + (H) * 32 + (wv & 3) * 8; \
    const int c_ = (l & 7) ^ (l >> 3); \
    const signed char* sB_ = Bq + (size_t)(n0 + rbase_ + (l >> 3)) * K_DIM \
                                + (size_t)(TAU) * 128 + c_ * 16; \
    __builtin_amdgcn_global_load_lds((const GAS void*)sB_, \
        (LAS void*)(lds + 65536 + (BUF) * 16384 + rbase_ * 128), 16, 0, 0); \
} while (0)

#define LOAD_SJ(DST, G) do { \
  _Pragma("unroll") \
  for (int j_ = 0; j_ < 4; ++j_) \
    DST[j_] = scalesT[(size_t)(G) * N_DIM + n0 + wc * 64 + j_ * 16 + lr]; \
} while (0)

#define PHASE(B, MH, NH, S0, S1) do { \
  i32x4 aF0_[2], aF1_[2], bF0_[2], bF1_[2]; \
  _Pragma("unroll") \
  for (int nj = 0; nj < 2; ++nj) { \
    const int rb = wc * 64 + (NH) * 32 + nj * 16 + lr; \
    const signed char* bp = lds + 65536 + (B) * 16384 + rb * 128; \
    bF0_[nj] = *(const i32x4*)(bp + ((quad       ^ (rb & 7)) << 4)); \
    bF1_[nj] = *(const i32x4*)(bp + (((4 | quad) ^ (rb & 7)) << 4)); \
  } \
  _Pragma("unroll") \
  for (int mi = 0; mi < 2; ++mi) { \
    const int ra = wr * 64 + (MH) * 32 + mi * 16 + lr; \
    const signed char* ap = lds + (B) * 32768 + ra * 128; \
    aF0_[mi] = *(const i32x4*)(ap + ((quad       ^ (ra & 7)) << 4)); \
    aF1_[mi] = *(const i32x4*)(ap + (((4 | quad) ^ (ra & 7)) << 4)); \
  } \
  i32x4 ci_[2][2]; \
  __builtin_amdgcn_s_setprio(1); \
  _Pragma("unroll") \
  for (int mi = 0; mi < 2; ++mi) { \
    ci_[mi][0] = __builtin_amdgcn_mfma_i32_16x16x64_i8(aF0_[mi], bF0_[0], izero, 0, 0, 0); \
    ci_[mi][1] = __builtin_amdgcn_mfma_i32_16x16x64_i8(aF0_[mi], bF0_[1], izero, 0, 0, 0); \
  } \
  _Pragma("unroll") \
  for (int mi = 0; mi < 2; ++mi) { \
    ci_[mi][0] = __builtin_amdgcn_mfma_i32_16x16x64_i8(aF1_[mi], bF1_[0], ci_[mi][0], 0, 0, 0); \
    ci_[mi][1] = __builtin_amdgcn_mfma_i32_16x16x64_i8(aF1_[mi], bF1_[1], ci_[mi][1], 0, 0, 0); \
  } \
  __builtin_amdgcn_s_setprio(0); \
  _Pragma("unroll") \
  for (int mi = 0; mi < 2; ++mi) \
    _Pragma("unroll") \
    for (int r = 0; r < 4; ++r) { \
      accf[(MH) * 2 + mi][(NH) * 2 + 0][r] += (S0) * (float)ci_[mi][0][r]; \
      accf[(MH) * 2 + mi][(NH) * 2 + 1][r] += (S1) * (float)ci_[mi][1][r]; \
    } \
} while (0)

#define VMW(N) asm volatile("s_waitcnt vmcnt(" #N ")" ::: "memory")
#define CLB()  asm volatile("" ::: "memory")
#define BAR()  __builtin_amdgcn_s_barrier()

__global__ __launch_bounds__(512)
__attribute__((amdgpu_waves_per_eu(2, 2)))
void gemm_i8(const signed char* __restrict__ Aq,
             const signed char* __restrict__ Bq,
             const float* __restrict__ scalesT,
             const float* __restrict__ sx,
             const float* __restrict__ bias,
             float* __restrict__ C) {
    __shared__ signed char lds[98304];

    const int tid  = threadIdx.x;
    const int l    = tid & 63;
    const int wv   = tid >> 6;      // 0..7
    const int wr   = wv >> 1;       // 0..3  (M quarter of 256)
    const int wc   = wv & 1;        // 0..1  (N half of 128)
    const int lr   = l & 15;
    const int quad = l >> 4;

    // XCD-aware swizzle: 1024 wgs = 8 XCDs x 128; per-XCD 8x16 tile rect (bijective).
    const int bid = blockIdx.x;
    const int xcd = bid & 7, kk = bid >> 3;          // kk in [0,128)
    const int by = (xcd >> 1) * 8 + (kk & 7);        // m-tile 0..31 (256-row tiles)
    const int bx = (xcd & 1) * 16 + (kk >> 3);       // n-tile 0..31 (128-col tiles)
    const int m0 = by * 256, n0 = bx * 128;

    float accf[4][4][4];
#pragma unroll
    for (int i = 0; i < 4; ++i)
#pragma unroll
        for (int j = 0; j < 4; ++j)
#pragma unroll
            for (int r = 0; r < 4; ++r) accf[i][j][r] = 0.f;

    const i32x4 izero = {0, 0, 0, 0};
    float sjc0[4], sjc1[4], sjn0[4], sjn1[4];

    // Prologue: scales for tiles 0,1; stage tile 0 into buf0 (steady-state order).
    LOAD_SJ(sjc0, 0);
    LOAD_SJ(sjc1, 1);
    STAGE_AH(0, 0, 0);
    STAGE_BH(0, 0, 0);
    STAGE_BH(0, 1, 0);
    STAGE_AH(0, 1, 0);
    VMW(3);
    BAR();

#pragma unroll 1
    for (int it = 0; it < 16; ++it) {
        const int tb  = it * 2 + 1;
        const int tn0 = (it * 2 + 2) & 31;
        const int tn1 = (it * 2 + 3) & 31;

        STAGE_AH(1, 0, tb); LOAD_SJ(sjn0, tn0);
        PHASE(0, 0, 0, sjc0[0], sjc0[1]);
        VMW(8); BAR();

        STAGE_BH(1, 0, tb);
        PHASE(0, 0, 1, sjc0[2], sjc0[3]);
        VMW(7); BAR();

        STAGE_BH(1, 1, tb);
        PHASE(0, 1, 0, sjc0[0], sjc0[1]);
        CLB(); BAR();

        STAGE_AH(1, 1, tb);
        PHASE(0, 1, 1, sjc0[2], sjc0[3]);
        VMW(3); BAR();

        STAGE_AH(0, 0, tn0); LOAD_SJ(sjn1, tn1);
        PHASE(1, 0, 0, sjc1[0], sjc1[1]);
        VMW(8); BAR();

        STAGE_BH(0, 0, tn0);
        PHASE(1, 0, 1, sjc1[2], sjc1[3]);
        VMW(7); BAR();

        STAGE_BH(0, 1, tn0);
        PHASE(1, 1, 0, sjc1[0], sjc1[1]);
        CLB(); BAR();

        STAGE_AH(0, 1, tn0);
        PHASE(1, 1, 1, sjc1[2], sjc1[3]);
        VMW(3); BAR();

#pragma unroll
        for (int j = 0; j < 4; ++j) { sjc0[j] = sjn0[j]; sjc1[j] = sjn1[j]; }
    }

    // Drain leftover wrap-staged DMA before the block exits.
    asm volatile("s_waitcnt vmcnt(0)" ::: "memory");

    // Epilogue: C/D layout col=lane&15, row=quad*4+reg (verified, dtype-independent)
    float sxr[4][4];
#pragma unroll
    for (int i = 0; i < 4; ++i)
#pragma unroll
        for (int r = 0; r < 4; ++r)
            sxr[i][r] = sx[m0 + wr * 64 + i * 16 + quad * 4 + r];
#pragma unroll
    for (int j = 0; j < 4; ++j) {
        const int gn = n0 + wc * 64 + j * 16 + lr;
        const float bv = bias[gn];
#pragma unroll
        for (int i = 0; i < 4; ++i) {
            const size_t gm = (size_t)m0 + wr * 64 + i * 16 + quad * 4;
#pragma unroll
            for (int r = 0; r < 4; ++r)
                C[(gm + r) * N_DIM + gn] = accf[i][j][r] * sxr[i][r] + bv;
        }
    }
}

extern "C" void kernel_launch(void* const* d_in, const int* in_sizes, int n_in,
                              void* d_out, int out_size, void* d_ws, size_t ws_size,
                              hipStream_t stream) {
    const float* x      = (const float*)d_in[0];   // [4,2048,4096] fp32
    const int*   wp     = (const int*)d_in[1];     // [4096,2048] int32 (uint8 semantics)
    const float* scales = (const float*)d_in[2];   // [4096,32]
    const float* bias   = (const float*)d_in[4];   // [4096]
    float* out = (float*)d_out;

    signed char* Xq = (signed char*)d_ws;                                   // 32 MB
    signed char* Wq = (signed char*)d_ws + (size_t)M_DIM * K_DIM;           // +16 MB
    float* sx  = (float*)((char*)d_ws + (size_t)M_DIM * K_DIM + (size_t)N_DIM * K_DIM);          // +32 KB
    float* scT = (float*)((char*)d_ws + (size_t)M_DIM * K_DIM + (size_t)N_DIM * K_DIM + 32768);  // +512 KB

    quant_x<<<M_DIM, 256, 0, stream>>>(x, Xq, sx);
    unpack_w<<<(N_DIM * (K_DIM / 2) / 4) / 256, 256, 0, stream>>>(wp, Wq);
    transp_scales<<<(N_DIM * 32) / 256, 256, 0, stream>>>(scales, scT);
    gemm_i8<<<dim3(1024), 512, 0, stream>>>(Xq, Wq, scT, sx, bias, out);
}